// Round 1
// baseline (64.629 us; speedup 1.0000x reference)
//
#include <hip/hip_runtime.h>
#include <hip/hip_bf16.h>

// HeadUpdator: fused bilinear-upsample+sigmoid+einsum (MFMA) + per-row gating MLP.
// feat (8,64,256,256) f32, head (8,80,64,1) f32, pred (8,80,128,128) f32 -> out (8,80,64,1,1) f32.

using bf16x8 = __attribute__((ext_vector_type(8))) short;
using f32x4  = __attribute__((ext_vector_type(4))) float;

#define NPART 64  // row-groups per batch in kernel 1 (each covers 4 output rows)

__device__ __forceinline__ unsigned pk2(float lo, float hi) {
  union { __hip_bfloat162 h2; unsigned u; } cv;
  cv.h2 = __float22bfloat162_rn(make_float2(lo, hi));
  return cv.u;
}
__device__ __forceinline__ float bf2f(unsigned short s) {
  return __uint_as_float(((unsigned)s) << 16);
}

// ---------------- Kernel 1: assemble partials ----------------
// grid = 8*64 blocks, 256 threads. Block (b, rb) covers output rows h = rb*4..rb*4+3.
// Per row: v-lerp pred -> yrow (bf16), h-lerp+sigmoid -> Plds[80][256] (bf16),
// then 4 waves x (N-tile of 16 ch) MFMA over the row's 256 pixels.
__global__ __launch_bounds__(256) void k_assemble(
    const float* __restrict__ feat, const float* __restrict__ pred,
    float* __restrict__ partial) {
  __shared__ __align__(16) unsigned short yrow[80 * 136];  // padded stride 136
  __shared__ __align__(16) unsigned short Plds[80 * 264];  // padded stride 264

  const int tid = threadIdx.x;
  const int b  = blockIdx.x >> 6;
  const int rb = blockIdx.x & 63;
  const int wid = tid >> 6, l = tid & 63;
  const int ch16 = l & 15, kg = l >> 4;
  const int c0 = wid << 4;

  f32x4 acc[5] = {};
  const float* fbase0 = feat + (((size_t)(b * 64 + c0 + ch16)) << 16);

  for (int it = 0; it < 4; ++it) {
    const int h = rb * 4 + it;
    const int p = h & 1, j = h >> 1;
    int r0, r1; float wy0, wy1;
    // jax.image.resize half-pixel: even h=2j -> rows (j-1,j) w=(.25,.75); odd -> (j,j+1) w=(.75,.25).
    // Clamped duplicate rows reproduce the renormalized edge weights exactly.
    if (p == 0) { r0 = (j > 0) ? j - 1 : 0; r1 = j; wy0 = 0.25f; wy1 = 0.75f; }
    else        { r0 = j; r1 = (j < 127) ? j + 1 : 127; wy0 = 0.75f; wy1 = 0.25f; }

    // Phase 1: vertical lerp -> yrow[n][0..127] (bf16). 80*32 float4-tasks.
    #pragma unroll
    for (int i = 0; i < 10; ++i) {
      const int id = tid + 256 * i;
      const int n = id >> 5, cg = id & 31;
      const float* pb = pred + (((size_t)(b * 80 + n)) << 14);
      const float4 v0 = *(const float4*)(pb + (r0 << 7) + cg * 4);
      const float4 v1 = *(const float4*)(pb + (r1 << 7) + cg * 4);
      uint2 s;
      s.x = pk2(wy0 * v0.x + wy1 * v1.x, wy0 * v0.y + wy1 * v1.y);
      s.y = pk2(wy0 * v0.z + wy1 * v1.z, wy0 * v0.w + wy1 * v1.w);
      *(uint2*)&yrow[n * 136 + cg * 4] = s;
    }
    __syncthreads();

    // Phase 2: horizontal lerp + sigmoid -> Plds[n][0..255] (bf16). 80*32 8-pixel tasks.
    // sigmoid(0.25a+0.75b) = rcp(1+exp2(-log2e*(0.25a+0.75b))): fold -log2e into lerp weights.
    #pragma unroll
    for (int i = 0; i < 10; ++i) {
      const int id = tid + 256 * i;
      const int n = id >> 5, g = id & 31;
      float yv[6];
      #pragma unroll
      for (int k = 0; k < 6; ++k) {
        int col = 4 * g - 1 + k;
        col = col < 0 ? 0 : (col > 127 ? 127 : col);
        yv[k] = bf2f(yrow[n * 136 + col]);
      }
      float P[8];
      #pragma unroll
      for (int px = 0; px < 8; ++px) {
        const int hf = px >> 1;
        float v;
        if ((px & 1) == 0) v = -0.36067376f * yv[hf]     + -1.08202128f * yv[hf + 1];
        else               v = -1.08202128f * yv[hf + 1] + -0.36067376f * yv[hf + 2];
        P[px] = __builtin_amdgcn_rcpf(1.0f + __builtin_amdgcn_exp2f(v));
      }
      uint4 s;
      s.x = pk2(P[0], P[1]); s.y = pk2(P[2], P[3]);
      s.z = pk2(P[4], P[5]); s.w = pk2(P[6], P[7]);
      *(uint4*)&Plds[n * 264 + g * 8] = s;
    }
    __syncthreads();

    // Phase 3: MFMA. Wave wid owns channels c0..c0+15; loops all 5 M-tiles, 8 k-steps.
    const float* fb = fbase0 + h * 256;
    #pragma unroll
    for (int ks = 0; ks < 8; ++ks) {
      const int pw = ks * 32 + kg * 8;
      const float4 f0 = *(const float4*)(fb + pw);
      const float4 f1 = *(const float4*)(fb + pw + 4);
      union { uint4 u; bf16x8 v; } bu;
      bu.u.x = pk2(f0.x, f0.y); bu.u.y = pk2(f0.z, f0.w);
      bu.u.z = pk2(f1.x, f1.y); bu.u.w = pk2(f1.z, f1.w);
      #pragma unroll
      for (int m = 0; m < 5; ++m) {
        const bf16x8 af = *(const bf16x8*)&Plds[(m * 16 + ch16) * 264 + pw];
        acc[m] = __builtin_amdgcn_mfma_f32_16x16x32_bf16(af, bu.v, acc[m], 0, 0, 0);
      }
    }
    __syncthreads();
  }

  // D frag: col = lane&15 (channel), row = (lane>>4)*4 + q (class).
  float* po = partial + ((size_t)(b * NPART + rb)) * (80 * 64);
  #pragma unroll
  for (int m = 0; m < 5; ++m) {
    #pragma unroll
    for (int q = 0; q < 4; ++q) {
      const int n = m * 16 + kg * 4 + q;
      po[n * 64 + c0 + ch16] = acc[m][q];
    }
  }
}

// ---------------- Kernel 2: reduce + head-update chain ----------------
__device__ __forceinline__ float wred64(float v) {
  #pragma unroll
  for (int off = 32; off > 0; off >>= 1) v += __shfl_xor(v, off, 64);
  return v;
}
__device__ __forceinline__ float lnorm(float x, const float* __restrict__ g,
                                       const float* __restrict__ be, int l) {
  const float m = wred64(x) * 0.015625f;
  const float d = x - m;
  const float var = wred64(d * d) * 0.015625f;
  return d * rsqrtf(var + 1e-5f) * g[l] + be[l];
}
__device__ __forceinline__ float sigmf(float x) {
  return __builtin_amdgcn_rcpf(1.0f + __builtin_amdgcn_exp2f(-1.44269504f * x));
}

__global__ __launch_bounds__(256) void k_head(
    const float* __restrict__ partial, const float* __restrict__ head,
    const float* __restrict__ Wpt, const float* __restrict__ bpt,
    const float* __restrict__ Wht, const float* __restrict__ bht,
    const float* __restrict__ Wpg, const float* __restrict__ bpg,
    const float* __restrict__ Whg, const float* __restrict__ bhg,
    const float* __restrict__ Wfc, const float* __restrict__ bfc,
    const float* __restrict__ g_pin, const float* __restrict__ be_pin,
    const float* __restrict__ g_hin, const float* __restrict__ be_hin,
    const float* __restrict__ g_pout, const float* __restrict__ be_pout,
    const float* __restrict__ g_hout, const float* __restrict__ be_hout,
    const float* __restrict__ g_fc, const float* __restrict__ be_fc,
    float* __restrict__ out) {
  __shared__ float rows[4][4][64];  // [wave][{a, hd, gate, upd}][c]
  const int tid = threadIdx.x, wid = tid >> 6, l = tid & 63;
  const int r = blockIdx.x * 4 + wid;   // grid=160 -> r in [0,640)
  const int b = r / 80, n = r % 80;

  // reduce 64 partials -> assemble row a[r][:]
  const float* pp = partial + (size_t)b * (NPART * 80 * 64) + n * 64 + l;
  float a_c = 0.f;
  #pragma unroll 8
  for (int jj = 0; jj < NPART; ++jj) a_c += pp[(size_t)jj * (80 * 64)];
  rows[wid][0][l] = a_c;
  rows[wid][1][l] = head[(size_t)r * 64 + l];
  __syncthreads();

  float pf_in = bpt[l], pf_out = bpt[64 + l];
  float hf_in = bht[l], hf_out = bht[64 + l];
  #pragma unroll 8
  for (int c = 0; c < 64; ++c) {
    const float av = rows[wid][0][c];
    const float hv = rows[wid][1][c];
    pf_in  += av * Wpt[c * 128 + l];
    pf_out += av * Wpt[c * 128 + 64 + l];
    hf_in  += hv * Wht[c * 128 + l];
    hf_out += hv * Wht[c * 128 + 64 + l];
  }
  const float gate = hf_in * pf_in;
  rows[wid][2][l] = gate;
  __syncthreads();

  float hg = bhg[l], pg = bpg[l];
  #pragma unroll 8
  for (int c = 0; c < 64; ++c) {
    const float gv = rows[wid][2][c];
    hg += gv * Whg[c * 64 + l];
    pg += gv * Wpg[c * 64 + l];
  }
  const float head_gate = sigmf(lnorm(hg, g_hin, be_hin, l));
  const float pred_gate = sigmf(lnorm(pg, g_pin, be_pin, l));
  const float hfo = lnorm(hf_out, g_hout, be_hout, l);
  const float pfo = lnorm(pf_out, g_pout, be_pout, l);
  const float upd = pred_gate * pfo + head_gate * hfo;
  rows[wid][3][l] = upd;
  __syncthreads();

  float fc = bfc[l];
  #pragma unroll 8
  for (int c = 0; c < 64; ++c)
    fc += rows[wid][3][c] * Wfc[c * 64 + l];
  float o = lnorm(fc, g_fc, be_fc, l);
  o = fmaxf(o, 0.f);
  out[(size_t)r * 64 + l] = o;
}

extern "C" void kernel_launch(void* const* d_in, const int* in_sizes, int n_in,
                              void* d_out, int out_size, void* d_ws, size_t ws_size,
                              hipStream_t stream) {
  const float* feat   = (const float*)d_in[0];
  const float* head   = (const float*)d_in[1];
  const float* pred   = (const float*)d_in[2];
  const float* Wpt    = (const float*)d_in[3];
  const float* bpt    = (const float*)d_in[4];
  const float* Wht    = (const float*)d_in[5];
  const float* bht    = (const float*)d_in[6];
  const float* Wpg    = (const float*)d_in[7];
  const float* bpg    = (const float*)d_in[8];
  const float* Whg    = (const float*)d_in[9];
  const float* bhg    = (const float*)d_in[10];
  const float* Wfc    = (const float*)d_in[11];
  const float* bfc    = (const float*)d_in[12];
  const float* g_pin  = (const float*)d_in[13];
  const float* be_pin = (const float*)d_in[14];
  const float* g_hin  = (const float*)d_in[15];
  const float* be_hin = (const float*)d_in[16];
  const float* g_pout = (const float*)d_in[17];
  const float* be_pout= (const float*)d_in[18];
  const float* g_hout = (const float*)d_in[19];
  const float* be_hout= (const float*)d_in[20];
  const float* g_fc   = (const float*)d_in[21];
  const float* be_fc  = (const float*)d_in[22];
  float* out = (float*)d_out;
  float* partial = (float*)d_ws;  // needs 8*64*80*64*4 = 10.5 MB

  hipLaunchKernelGGL(k_assemble, dim3(8 * NPART), dim3(256), 0, stream,
                     feat, pred, partial);
  hipLaunchKernelGGL(k_head, dim3(160), dim3(256), 0, stream,
                     partial, head, Wpt, bpt, Wht, bht, Wpg, bpg, Whg, bhg,
                     Wfc, bfc, g_pin, be_pin, g_hin, be_hin, g_pout, be_pout,
                     g_hout, be_hout, g_fc, be_fc, out);
}